// Round 7
// baseline (1897.220 us; speedup 1.0000x reference)
//
#include <hip/hip_runtime.h>

// Problem constants (match reference)
constexpr int N  = 100000;   // nodes
constexpr int E  = 3200000;  // edges
constexpr int G  = 128;      // graphs
constexpr int H  = 64;       // hidden
constexpr int NP = 8;        // channel passes for layer-2 aggregation
constexpr int CP = H / NP;   // channels per pass (8)

// ---------------------------------------------------------------------------
// K1: in-degree counts (dst occurrences); self-loop added later as +1
__global__ __launch_bounds__(256) void k_count(const int* __restrict__ dst,
                                               int* __restrict__ cnt) {
    int e = blockIdx.x * 256 + threadIdx.x;
    if (e < E) atomicAdd(&cnt[dst[e]], 1);
}

// K2: dinv = rsqrt(deg), gx = x * dinv (pre-scaled 2-channel features)
__global__ __launch_bounds__(256) void k_dinv(const float* __restrict__ x,
                                              const int* __restrict__ cnt,
                                              float* __restrict__ dinv,
                                              float2* __restrict__ gx) {
    int v = blockIdx.x * 256 + threadIdx.x;
    if (v < N) {
        float d = rsqrtf((float)(cnt[v] + 1));
        dinv[v] = d;
        float2 xv = ((const float2*)x)[v];
        gx[v] = make_float2(xv.x * d, xv.y * d);
    }
}

// K3: single-block exclusive scan of cnt -> offs (and cursor copy).
__global__ __launch_bounds__(1024) void k_scan(const int* __restrict__ cnt,
                                               int* __restrict__ offs,
                                               int* __restrict__ cursor) {
    constexpr int T = 1024;
    constexpr int PER = (N + T - 1) / T;  // 98
    int tid = threadIdx.x;
    int begin = tid * PER;
    int end = begin + PER; if (end > N) end = N;

    int total = 0;
    for (int i = begin; i < end; ++i) total += cnt[i];

    __shared__ int wsum[16];
    int lane = tid & 63, wid = tid >> 6;
    int incl = total;
    #pragma unroll
    for (int off = 1; off < 64; off <<= 1) {
        int t = __shfl_up(incl, off);
        if (lane >= off) incl += t;
    }
    if (lane == 63) wsum[wid] = incl;
    __syncthreads();
    if (wid == 0 && lane < 16) {
        int w = wsum[lane];
        #pragma unroll
        for (int off = 1; off < 16; off <<= 1) {
            int t = __shfl_up(w, off);
            if (lane >= off) w += t;
        }
        wsum[lane] = w;  // inclusive over waves
    }
    __syncthreads();
    int waveBase = (wid == 0) ? 0 : wsum[wid - 1];
    int run = waveBase + (incl - total);  // exclusive prefix of this thread
    for (int i = begin; i < end; ++i) {
        offs[i] = run;
        cursor[i] = run;
        run += cnt[i];
    }
}

// K4: fill CSR (src indices grouped by dst)
__global__ __launch_bounds__(256) void k_fill(const int* __restrict__ src,
                                              const int* __restrict__ dst,
                                              int* __restrict__ cursor,
                                              int* __restrict__ csr) {
    int e = blockIdx.x * 256 + threadIdx.x;
    if (e < E) {
        int d = dst[e];
        int pos = atomicAdd(&cursor[d], 1);
        csr[pos] = src[e];
    }
}

// K5: layer-1 aggregation in 2-channel input space. One wave per node;
// gx (800KB) is L2-resident on every XCD, so gathers are L2 hits.
__global__ __launch_bounds__(256) void k_agg1(const int* __restrict__ csr,
                                              const int* __restrict__ offs,
                                              const int* __restrict__ cnt,
                                              const float* __restrict__ dinv,
                                              const float2* __restrict__ gx,
                                              float2* __restrict__ aggx) {
    int lane = threadIdx.x & 63;
    int v = (blockIdx.x * 256 + threadIdx.x) >> 6;
    if (v >= N) return;
    int start = offs[v], dg = cnt[v];
    float ax = 0.f, ay = 0.f;
    for (int i = lane; i < dg; i += 64) {
        int s = csr[start + i];
        float2 g = gx[s];
        ax += g.x; ay += g.y;
    }
    #pragma unroll
    for (int off = 1; off < 64; off <<= 1) {
        ax += __shfl_xor(ax, off);
        ay += __shfl_xor(ay, off);
    }
    if (lane == 0) {
        float d = dinv[v];
        float2 g = gx[v];
        aggx[v] = make_float2(d * (ax + g.x), d * (ay + g.y));
    }
}

// K6: per-node MLP: t = relu(aggx @ W1 + b1); g2 = (t @ W2) * dinv[v]
// Output written in channel-split layout: g2s[p][v][c8]  (p = pass, c8 = 0..7)
__global__ __launch_bounds__(256) void k_mlp(const float2* __restrict__ aggx,
                                             const float* __restrict__ W1,
                                             const float* __restrict__ b1,
                                             const float* __restrict__ W2,
                                             const float* __restrict__ dinv,
                                             float* __restrict__ g2s) {
    int lane = threadIdx.x & 63;
    int wave = (blockIdx.x * 256 + threadIdx.x) >> 6;
    int nw = gridDim.x * 4;

    float w2col[64];
    #pragma unroll
    for (int k = 0; k < 64; ++k) w2col[k] = W2[k * 64 + lane];
    float w10 = W1[lane], w11 = W1[64 + lane], bb = b1[lane];

    // split-layout store offset for this lane's channel
    size_t soff = (size_t)(lane >> 3) * ((size_t)N * CP) + (size_t)(lane & 7);

    for (int v = wave; v < N; v += nw) {
        float2 a = aggx[v];
        float tt = fmaxf(fmaf(a.y, w11, fmaf(a.x, w10, bb)), 0.f);
        float a0 = 0.f, a1 = 0.f, a2 = 0.f, a3 = 0.f;
        #pragma unroll
        for (int k = 0; k < 64; k += 4) {
            float t0 = __int_as_float(__builtin_amdgcn_readlane(__float_as_int(tt), k + 0));
            float t1 = __int_as_float(__builtin_amdgcn_readlane(__float_as_int(tt), k + 1));
            float t2 = __int_as_float(__builtin_amdgcn_readlane(__float_as_int(tt), k + 2));
            float t3 = __int_as_float(__builtin_amdgcn_readlane(__float_as_int(tt), k + 3));
            a0 = fmaf(t0, w2col[k + 0], a0);
            a1 = fmaf(t1, w2col[k + 1], a1);
            a2 = fmaf(t2, w2col[k + 2], a2);
            a3 = fmaf(t3, w2col[k + 3], a3);
        }
        g2s[soff + (size_t)v * CP] = ((a0 + a1) + (a2 + a3)) * dinv[v];
    }
}

// K7 (x8 passes): layer-2 aggregation over an L2-resident 3.2MB sub-table.
// Wave per node; lane = (edge_sub = lane>>3, ch = lane&7): 8 edges x 8 ch per
// iteration. Each 8-lane group loads its own csr index directly (broadcast
// 4B load), then gathers a 32B row slice — all L2 hits after warm-up.
__global__ __launch_bounds__(256) void k_agg2s(const int* __restrict__ csr,
                                               const int* __restrict__ offs,
                                               const int* __restrict__ cnt,
                                               const float* __restrict__ dinv,
                                               const float* __restrict__ b2p,   // b2 + p*8
                                               const float* __restrict__ tab,   // g2s + p*N*8
                                               const int* __restrict__ batch,
                                               float* __restrict__ pooledp,     // pooled + p*8
                                               int* __restrict__ cntg,
                                               int do_cnt) {
    int lane = threadIdx.x & 63;
    int v = (blockIdx.x * 256 + threadIdx.x) >> 6;
    if (v >= N) return;
    int es = lane >> 3;   // edge sub-slot 0..7
    int ch = lane & 7;    // channel 0..7
    int start = offs[v], dg = cnt[v];

    float acc = 0.f;
    int base = 0;
    while (base < dg) {
        #pragma unroll
        for (int it = 0; it < 8; ++it) {
            int e0 = base + it * 8;
            if (e0 >= dg) break;              // wave-uniform
            int e = e0 + es;
            bool ok = e < dg;
            int ec = ok ? e : (dg - 1);       // clamped, always in-bounds
            int row = csr[start + ec];        // 8 consecutive ints, broadcast x8
            float val = tab[(size_t)row * CP + ch];
            acc += ok ? val : 0.f;
        }
        base += 64;
    }

    // reduce across the 8 edge-slots (butterfly over lane bits 3..5)
    acc += __shfl_xor(acc, 8);
    acc += __shfl_xor(acc, 16);
    acc += __shfl_xor(acc, 32);

    if (lane < 8) {
        acc += tab[(size_t)v * CP + ch];      // self-loop term
        float o = fmaxf(fmaf(dinv[v], acc, b2p[ch]), 0.f);
        int b = batch[v];
        atomicAdd(&pooledp[b * 64 + ch], o);
        if (do_cnt && lane == 0) atomicAdd(&cntg[b], 1);
    }
}

// K8: final: out[g] = (pooled[g]/max(cnt,1)) . Wfc + bfc
__global__ __launch_bounds__(64) void k_final(const float* __restrict__ pooled,
                                              const int* __restrict__ cntg,
                                              const float* __restrict__ Wfc,
                                              const float* __restrict__ bfc,
                                              float* __restrict__ out) {
    int g = blockIdx.x;
    int j = threadIdx.x;  // 64
    float c = fmaxf((float)cntg[g], 1.f);
    float p = (pooled[g * 64 + j] / c) * Wfc[j];
    #pragma unroll
    for (int off = 32; off >= 1; off >>= 1) p += __shfl_down(p, off);
    if (j == 0) out[g] = p + bfc[0];
}

// ---------------------------------------------------------------------------
extern "C" void kernel_launch(void* const* d_in, const int* in_sizes, int n_in,
                              void* d_out, int out_size, void* d_ws, size_t ws_size,
                              hipStream_t stream) {
    const float* x     = (const float*)d_in[0];
    const int*   edge  = (const int*)d_in[1];
    const int*   batch = (const int*)d_in[2];
    const float* W1    = (const float*)d_in[3];
    const float* b1    = (const float*)d_in[4];
    const float* W2    = (const float*)d_in[5];
    const float* b2    = (const float*)d_in[6];
    const float* Wfc   = (const float*)d_in[7];
    const float* bfc   = (const float*)d_in[8];
    float* out = (float*)d_out;

    const int* src = edge;       // edge_index[0]
    const int* dst = edge + E;   // edge_index[1]

    // workspace layout (1 KiB aligned regions), ~40 MB total
    char* base = (char*)d_ws;
    size_t o = 0;
    auto alloc = [&](size_t bytes) -> void* {
        void* p = base + o;
        o += (bytes + 1023) & ~size_t(1023);
        return p;
    };
    int*    cnt    = (int*)alloc((size_t)N * 4);
    float*  dinv   = (float*)alloc((size_t)N * 4);
    float2* gx     = (float2*)alloc((size_t)N * 8);
    float2* aggx   = (float2*)alloc((size_t)N * 8);
    int*    offs   = (int*)alloc((size_t)N * 4);
    int*    cursor = (int*)alloc((size_t)N * 4);
    int*    csr    = (int*)alloc((size_t)E * 4 + 1024);  // +pad
    float*  g2s    = (float*)alloc((size_t)N * H * 4);   // [NP][N][CP]
    float*  pooled = (float*)alloc((size_t)G * H * 4);
    int*    cntg   = (int*)alloc((size_t)G * 4);

    hipMemsetAsync(cnt, 0, (size_t)N * 4, stream);
    hipMemsetAsync(pooled, 0, (size_t)G * H * 4, stream);
    hipMemsetAsync(cntg, 0, (size_t)G * 4, stream);

    k_count<<<(E + 255) / 256, 256, 0, stream>>>(dst, cnt);
    k_dinv<<<(N + 255) / 256, 256, 0, stream>>>(x, cnt, dinv, gx);
    k_scan<<<1, 1024, 0, stream>>>(cnt, offs, cursor);
    k_fill<<<(E + 255) / 256, 256, 0, stream>>>(src, dst, cursor, csr);
    k_agg1<<<(N + 3) / 4, 256, 0, stream>>>(csr, offs, cnt, dinv, gx, aggx);
    k_mlp<<<1024, 256, 0, stream>>>(aggx, W1, b1, W2, dinv, g2s);
    // 8 sequential channel passes — one 3.2MB sub-table hot in L2 at a time
    for (int p = 0; p < NP; ++p) {
        k_agg2s<<<(N + 3) / 4, 256, 0, stream>>>(
            csr, offs, cnt, dinv, b2 + p * CP,
            g2s + (size_t)p * N * CP, batch,
            pooled + p * CP, cntg, p == 0 ? 1 : 0);
    }
    k_final<<<G, 64, 0, stream>>>(pooled, cntg, Wfc, bfc, out);
}

// Round 9
// 1457.459 us; speedup vs baseline: 1.3017x; 1.3017x over previous
//
#include <hip/hip_runtime.h>

// Problem constants (match reference)
constexpr int N  = 100000;   // nodes
constexpr int E  = 3200000;  // edges
constexpr int G  = 128;      // graphs
constexpr int H  = 64;       // hidden

__device__ __forceinline__ unsigned short f32_to_bf16_rne(float x) {
    unsigned int u = __float_as_uint(x);
    unsigned int r = (u + 0x7FFFu + ((u >> 16) & 1u)) >> 16;
    return (unsigned short)r;
}
__device__ __forceinline__ float bf16_to_f32(unsigned short b) {
    return __uint_as_float(((unsigned int)b) << 16);
}

// ---------------------------------------------------------------------------
// K1: in-degree counts (dst occurrences); self-loop added later as +1
__global__ __launch_bounds__(256) void k_count(const int* __restrict__ dst,
                                               int* __restrict__ cnt) {
    int e = blockIdx.x * 256 + threadIdx.x;
    if (e < E) atomicAdd(&cnt[dst[e]], 1);
}

// K2: dinv = rsqrt(deg), gx = x * dinv (pre-scaled 2-channel features)
__global__ __launch_bounds__(256) void k_dinv(const float* __restrict__ x,
                                              const int* __restrict__ cnt,
                                              float* __restrict__ dinv,
                                              float2* __restrict__ gx) {
    int v = blockIdx.x * 256 + threadIdx.x;
    if (v < N) {
        float d = rsqrtf((float)(cnt[v] + 1));
        dinv[v] = d;
        float2 xv = ((const float2*)x)[v];
        gx[v] = make_float2(xv.x * d, xv.y * d);
    }
}

// K3: single-block exclusive scan of cnt -> offs (and cursor copy).
__global__ __launch_bounds__(1024) void k_scan(const int* __restrict__ cnt,
                                               int* __restrict__ offs,
                                               int* __restrict__ cursor) {
    constexpr int T = 1024;
    constexpr int PER = (N + T - 1) / T;  // 98
    int tid = threadIdx.x;
    int begin = tid * PER;
    int end = begin + PER; if (end > N) end = N;

    int total = 0;
    for (int i = begin; i < end; ++i) total += cnt[i];

    __shared__ int wsum[16];
    int lane = tid & 63, wid = tid >> 6;
    int incl = total;
    #pragma unroll
    for (int off = 1; off < 64; off <<= 1) {
        int t = __shfl_up(incl, off);
        if (lane >= off) incl += t;
    }
    if (lane == 63) wsum[wid] = incl;
    __syncthreads();
    if (wid == 0 && lane < 16) {
        int w = wsum[lane];
        #pragma unroll
        for (int off = 1; off < 16; off <<= 1) {
            int t = __shfl_up(w, off);
            if (lane >= off) w += t;
        }
        wsum[lane] = w;  // inclusive over waves
    }
    __syncthreads();
    int waveBase = (wid == 0) ? 0 : wsum[wid - 1];
    int run = waveBase + (incl - total);  // exclusive prefix of this thread
    for (int i = begin; i < end; ++i) {
        offs[i] = run;
        cursor[i] = run;
        run += cnt[i];
    }
}

// K4: fill CSR (src indices grouped by dst)
__global__ __launch_bounds__(256) void k_fill(const int* __restrict__ src,
                                              const int* __restrict__ dst,
                                              int* __restrict__ cursor,
                                              int* __restrict__ csr) {
    int e = blockIdx.x * 256 + threadIdx.x;
    if (e < E) {
        int d = dst[e];
        int pos = atomicAdd(&cursor[d], 1);
        csr[pos] = src[e];
    }
}

// K5: layer-1 aggregation in 2-channel input space. One wave per node,
// lane-per-edge: coalesced index load + 64 independent 8B gathers in flight.
__global__ __launch_bounds__(256) void k_agg1(const int* __restrict__ csr,
                                              const int* __restrict__ offs,
                                              const int* __restrict__ cnt,
                                              const float* __restrict__ dinv,
                                              const float2* __restrict__ gx,
                                              float2* __restrict__ aggx) {
    int lane = threadIdx.x & 63;
    int v = (blockIdx.x * 256 + threadIdx.x) >> 6;
    if (v >= N) return;
    int start = offs[v], dg = cnt[v];
    float ax = 0.f, ay = 0.f;
    for (int i = lane; i < dg; i += 64) {
        int s = csr[start + i];
        float2 g = gx[s];
        ax += g.x; ay += g.y;
    }
    #pragma unroll
    for (int off = 1; off < 64; off <<= 1) {
        ax += __shfl_xor(ax, off);
        ay += __shfl_xor(ay, off);
    }
    if (lane == 0) {
        float d = dinv[v];
        float2 g = gx[v];
        aggx[v] = make_float2(d * (ax + g.x), d * (ay + g.y));
    }
}

// K6: per-node MLP: t = relu(aggx @ W1 + b1); g2 = (t @ W2) * dinv[v]
// Output stored as bf16 rows [v][64] — halves the scattered-line count in K7.
__global__ __launch_bounds__(256) void k_mlp(const float2* __restrict__ aggx,
                                             const float* __restrict__ W1,
                                             const float* __restrict__ b1,
                                             const float* __restrict__ W2,
                                             const float* __restrict__ dinv,
                                             unsigned short* __restrict__ g2b) {
    int lane = threadIdx.x & 63;
    int wave = (blockIdx.x * 256 + threadIdx.x) >> 6;
    int nw = gridDim.x * 4;

    float w2col[64];
    #pragma unroll
    for (int k = 0; k < 64; ++k) w2col[k] = W2[k * 64 + lane];
    float w10 = W1[lane], w11 = W1[64 + lane], bb = b1[lane];

    for (int v = wave; v < N; v += nw) {
        float2 a = aggx[v];
        float tt = fmaxf(fmaf(a.y, w11, fmaf(a.x, w10, bb)), 0.f);
        float a0 = 0.f, a1 = 0.f, a2 = 0.f, a3 = 0.f;
        #pragma unroll
        for (int k = 0; k < 64; k += 4) {
            float t0 = __int_as_float(__builtin_amdgcn_readlane(__float_as_int(tt), k + 0));
            float t1 = __int_as_float(__builtin_amdgcn_readlane(__float_as_int(tt), k + 1));
            float t2 = __int_as_float(__builtin_amdgcn_readlane(__float_as_int(tt), k + 2));
            float t3 = __int_as_float(__builtin_amdgcn_readlane(__float_as_int(tt), k + 3));
            a0 = fmaf(t0, w2col[k + 0], a0);
            a1 = fmaf(t1, w2col[k + 1], a1);
            a2 = fmaf(t2, w2col[k + 2], a2);
            a3 = fmaf(t3, w2col[k + 3], a3);
        }
        float val = ((a0 + a1) + (a2 + a3)) * dinv[v];
        g2b[(size_t)v * 64 + lane] = f32_to_bf16_rne(val);
    }
}

// K7: layer-2 aggregation (wave per node) + relu + fused mean-pool atomics.
// bf16 rows: 128B per edge-gather (2 cache lines vs 4 for fp32).
// Indices preloaded 64-at-a-time coalesced, broadcast via readlane.
__global__ __launch_bounds__(256) void k_agg2(const int* __restrict__ csr,
                                              const int* __restrict__ offs,
                                              const int* __restrict__ cnt,
                                              const float* __restrict__ dinv,
                                              const float* __restrict__ b2,
                                              const unsigned short* __restrict__ g2b,
                                              const int* __restrict__ batch,
                                              float* __restrict__ pooled,
                                              int* __restrict__ cntg) {
    int lane = threadIdx.x & 63;
    int v = (blockIdx.x * 256 + threadIdx.x) >> 6;
    if (v >= N) return;
    int start = offs[v], dg = cnt[v];
    float acc = bf16_to_f32(g2b[(size_t)v * 64 + lane]);  // self-loop term

    int base = 0;
    while (base < dg) {
        int chunk = dg - base; if (chunk > 64) chunk = 64;
        int idx = csr[start + base + lane];  // coalesced; csr padded
        int i = 0;
        for (; i + 8 <= chunk; i += 8) {
            const unsigned short* r0 = g2b + (size_t)__builtin_amdgcn_readlane(idx, i + 0) * 64;
            const unsigned short* r1 = g2b + (size_t)__builtin_amdgcn_readlane(idx, i + 1) * 64;
            const unsigned short* r2 = g2b + (size_t)__builtin_amdgcn_readlane(idx, i + 2) * 64;
            const unsigned short* r3 = g2b + (size_t)__builtin_amdgcn_readlane(idx, i + 3) * 64;
            const unsigned short* r4 = g2b + (size_t)__builtin_amdgcn_readlane(idx, i + 4) * 64;
            const unsigned short* r5 = g2b + (size_t)__builtin_amdgcn_readlane(idx, i + 5) * 64;
            const unsigned short* r6 = g2b + (size_t)__builtin_amdgcn_readlane(idx, i + 6) * 64;
            const unsigned short* r7 = g2b + (size_t)__builtin_amdgcn_readlane(idx, i + 7) * 64;
            unsigned short u0 = r0[lane], u1 = r1[lane], u2 = r2[lane], u3 = r3[lane];
            unsigned short u4 = r4[lane], u5 = r5[lane], u6 = r6[lane], u7 = r7[lane];
            float f0 = bf16_to_f32(u0), f1 = bf16_to_f32(u1);
            float f2 = bf16_to_f32(u2), f3 = bf16_to_f32(u3);
            float f4 = bf16_to_f32(u4), f5 = bf16_to_f32(u5);
            float f6 = bf16_to_f32(u6), f7 = bf16_to_f32(u7);
            acc += ((f0 + f1) + (f2 + f3)) + ((f4 + f5) + (f6 + f7));
        }
        for (; i < chunk; ++i) {
            const unsigned short* r = g2b + (size_t)__builtin_amdgcn_readlane(idx, i) * 64;
            acc += bf16_to_f32(r[lane]);
        }
        base += chunk;
    }

    float o = fmaxf(fmaf(dinv[v], acc, b2[lane]), 0.f);
    int b = batch[v];
    atomicAdd(&pooled[b * 64 + lane], o);
    if (lane == 0) atomicAdd(&cntg[b], 1);
}

// K8: final: out[g] = (pooled[g]/max(cnt,1)) . Wfc + bfc
__global__ __launch_bounds__(64) void k_final(const float* __restrict__ pooled,
                                              const int* __restrict__ cntg,
                                              const float* __restrict__ Wfc,
                                              const float* __restrict__ bfc,
                                              float* __restrict__ out) {
    int g = blockIdx.x;
    int j = threadIdx.x;  // 64
    float c = fmaxf((float)cntg[g], 1.f);
    float p = (pooled[g * 64 + j] / c) * Wfc[j];
    #pragma unroll
    for (int off = 32; off >= 1; off >>= 1) p += __shfl_down(p, off);
    if (j == 0) out[g] = p + bfc[0];
}

// ---------------------------------------------------------------------------
extern "C" void kernel_launch(void* const* d_in, const int* in_sizes, int n_in,
                              void* d_out, int out_size, void* d_ws, size_t ws_size,
                              hipStream_t stream) {
    const float* x     = (const float*)d_in[0];
    const int*   edge  = (const int*)d_in[1];
    const int*   batch = (const int*)d_in[2];
    const float* W1    = (const float*)d_in[3];
    const float* b1    = (const float*)d_in[4];
    const float* W2    = (const float*)d_in[5];
    const float* b2    = (const float*)d_in[6];
    const float* Wfc   = (const float*)d_in[7];
    const float* bfc   = (const float*)d_in[8];
    float* out = (float*)d_out;

    const int* src = edge;       // edge_index[0]
    const int* dst = edge + E;   // edge_index[1]

    // workspace layout (1 KiB aligned regions)
    char* base = (char*)d_ws;
    size_t o = 0;
    auto alloc = [&](size_t bytes) -> void* {
        void* p = base + o;
        o += (bytes + 1023) & ~size_t(1023);
        return p;
    };
    int*    cnt    = (int*)alloc((size_t)N * 4);
    float*  dinv   = (float*)alloc((size_t)N * 4);
    float2* gx     = (float2*)alloc((size_t)N * 8);
    float2* aggx   = (float2*)alloc((size_t)N * 8);
    int*    offs   = (int*)alloc((size_t)N * 4);
    int*    cursor = (int*)alloc((size_t)N * 4);
    int*    csr    = (int*)alloc((size_t)E * 4 + 1024);   // +pad for 64-lane over-read
    unsigned short* g2b = (unsigned short*)alloc((size_t)N * H * 2);  // bf16 rows
    float*  pooled = (float*)alloc((size_t)G * H * 4);
    int*    cntg   = (int*)alloc((size_t)G * 4);

    hipMemsetAsync(cnt, 0, (size_t)N * 4, stream);
    hipMemsetAsync(pooled, 0, (size_t)G * H * 4, stream);
    hipMemsetAsync(cntg, 0, (size_t)G * 4, stream);

    k_count<<<(E + 255) / 256, 256, 0, stream>>>(dst, cnt);
    k_dinv<<<(N + 255) / 256, 256, 0, stream>>>(x, cnt, dinv, gx);
    k_scan<<<1, 1024, 0, stream>>>(cnt, offs, cursor);
    k_fill<<<(E + 255) / 256, 256, 0, stream>>>(src, dst, cursor, csr);
    k_agg1<<<(N + 3) / 4, 256, 0, stream>>>(csr, offs, cnt, dinv, gx, aggx);
    k_mlp<<<1024, 256, 0, stream>>>(aggx, W1, b1, W2, dinv, g2b);
    k_agg2<<<(N + 3) / 4, 256, 0, stream>>>(csr, offs, cnt, dinv, b2, g2b, batch, pooled, cntg);
    k_final<<<G, 64, 0, stream>>>(pooled, cntg, Wfc, bfc, out);
}

// Round 13
// 1437.624 us; speedup vs baseline: 1.3197x; 1.0138x over previous
//
#include <hip/hip_runtime.h>

// Problem constants (match reference)
constexpr int N  = 100000;   // nodes
constexpr int E  = 3200000;  // edges
constexpr int G  = 128;      // graphs
constexpr int H  = 64;       // hidden

__device__ __forceinline__ unsigned short f32_to_bf16_rne(float x) {
    unsigned int u = __float_as_uint(x);
    unsigned int r = (u + 0x7FFFu + ((u >> 16) & 1u)) >> 16;
    return (unsigned short)r;
}
__device__ __forceinline__ float bf16_to_f32(unsigned short b) {
    return __uint_as_float(((unsigned int)b) << 16);
}
__device__ __forceinline__ float bflo(unsigned int u) { return __uint_as_float(u << 16); }
__device__ __forceinline__ float bfhi(unsigned int u) { return __uint_as_float(u & 0xFFFF0000u); }

// ---------------------------------------------------------------------------
// K1: in-degree counts (dst occurrences); self-loop added later as +1
__global__ __launch_bounds__(256) void k_count(const int* __restrict__ dst,
                                               int* __restrict__ cnt) {
    int e = blockIdx.x * 256 + threadIdx.x;
    if (e < E) atomicAdd(&cnt[dst[e]], 1);
}

// K2: dinv = rsqrt(deg), gx = x * dinv (pre-scaled 2-channel features)
__global__ __launch_bounds__(256) void k_dinv(const float* __restrict__ x,
                                              const int* __restrict__ cnt,
                                              float* __restrict__ dinv,
                                              float2* __restrict__ gx) {
    int v = blockIdx.x * 256 + threadIdx.x;
    if (v < N) {
        float d = rsqrtf((float)(cnt[v] + 1));
        dinv[v] = d;
        float2 xv = ((const float2*)x)[v];
        gx[v] = make_float2(xv.x * d, xv.y * d);
    }
}

// K3: single-block exclusive scan of cnt -> offs (and cursor copy).
__global__ __launch_bounds__(1024) void k_scan(const int* __restrict__ cnt,
                                               int* __restrict__ offs,
                                               int* __restrict__ cursor) {
    constexpr int T = 1024;
    constexpr int PER = (N + T - 1) / T;  // 98
    int tid = threadIdx.x;
    int begin = tid * PER;
    int end = begin + PER; if (end > N) end = N;

    int total = 0;
    for (int i = begin; i < end; ++i) total += cnt[i];

    __shared__ int wsum[16];
    int lane = tid & 63, wid = tid >> 6;
    int incl = total;
    #pragma unroll
    for (int off = 1; off < 64; off <<= 1) {
        int t = __shfl_up(incl, off);
        if (lane >= off) incl += t;
    }
    if (lane == 63) wsum[wid] = incl;
    __syncthreads();
    if (wid == 0 && lane < 16) {
        int w = wsum[lane];
        #pragma unroll
        for (int off = 1; off < 16; off <<= 1) {
            int t = __shfl_up(w, off);
            if (lane >= off) w += t;
        }
        wsum[lane] = w;  // inclusive over waves
    }
    __syncthreads();
    int waveBase = (wid == 0) ? 0 : wsum[wid - 1];
    int run = waveBase + (incl - total);  // exclusive prefix of this thread
    for (int i = begin; i < end; ++i) {
        offs[i] = run;
        cursor[i] = run;
        run += cnt[i];
    }
}

// K4: fill CSR (src indices grouped by dst)
__global__ __launch_bounds__(256) void k_fill(const int* __restrict__ src,
                                              const int* __restrict__ dst,
                                              int* __restrict__ cursor,
                                              int* __restrict__ csr) {
    int e = blockIdx.x * 256 + threadIdx.x;
    if (e < E) {
        int d = dst[e];
        int pos = atomicAdd(&cursor[d], 1);
        csr[pos] = src[e];
    }
}

// K5: layer-1 aggregation in 2-channel input space. One wave per node,
// lane-per-edge: coalesced index load + 64 independent 8B gathers in flight.
__global__ __launch_bounds__(256) void k_agg1(const int* __restrict__ csr,
                                              const int* __restrict__ offs,
                                              const int* __restrict__ cnt,
                                              const float* __restrict__ dinv,
                                              const float2* __restrict__ gx,
                                              float2* __restrict__ aggx) {
    int lane = threadIdx.x & 63;
    int v = (blockIdx.x * 256 + threadIdx.x) >> 6;
    if (v >= N) return;
    int start = offs[v], dg = cnt[v];
    float ax = 0.f, ay = 0.f;
    for (int i = lane; i < dg; i += 64) {
        int s = csr[start + i];
        float2 g = gx[s];
        ax += g.x; ay += g.y;
    }
    #pragma unroll
    for (int off = 1; off < 64; off <<= 1) {
        ax += __shfl_xor(ax, off);
        ay += __shfl_xor(ay, off);
    }
    if (lane == 0) {
        float d = dinv[v];
        float2 g = gx[v];
        aggx[v] = make_float2(d * (ax + g.x), d * (ay + g.y));
    }
}

// K6: per-node MLP: t = relu(aggx @ W1 + b1); g2 = (t @ W2) * dinv[v]
// Output stored as bf16 rows [v][64] (128B rows, 2 cache lines).
__global__ __launch_bounds__(256) void k_mlp(const float2* __restrict__ aggx,
                                             const float* __restrict__ W1,
                                             const float* __restrict__ b1,
                                             const float* __restrict__ W2,
                                             const float* __restrict__ dinv,
                                             unsigned short* __restrict__ g2b) {
    int lane = threadIdx.x & 63;
    int wave = (blockIdx.x * 256 + threadIdx.x) >> 6;
    int nw = gridDim.x * 4;

    float w2col[64];
    #pragma unroll
    for (int k = 0; k < 64; ++k) w2col[k] = W2[k * 64 + lane];
    float w10 = W1[lane], w11 = W1[64 + lane], bb = b1[lane];

    for (int v = wave; v < N; v += nw) {
        float2 a = aggx[v];
        float tt = fmaxf(fmaf(a.y, w11, fmaf(a.x, w10, bb)), 0.f);
        float a0 = 0.f, a1 = 0.f, a2 = 0.f, a3 = 0.f;
        #pragma unroll
        for (int k = 0; k < 64; k += 4) {
            float t0 = __int_as_float(__builtin_amdgcn_readlane(__float_as_int(tt), k + 0));
            float t1 = __int_as_float(__builtin_amdgcn_readlane(__float_as_int(tt), k + 1));
            float t2 = __int_as_float(__builtin_amdgcn_readlane(__float_as_int(tt), k + 2));
            float t3 = __int_as_float(__builtin_amdgcn_readlane(__float_as_int(tt), k + 3));
            a0 = fmaf(t0, w2col[k + 0], a0);
            a1 = fmaf(t1, w2col[k + 1], a1);
            a2 = fmaf(t2, w2col[k + 2], a2);
            a3 = fmaf(t3, w2col[k + 3], a3);
        }
        float val = ((a0 + a1) + (a2 + a3)) * dinv[v];
        g2b[(size_t)v * 64 + lane] = f32_to_bf16_rne(val);
    }
}

// K7: layer-2 aggregation + relu + fused mean-pool atomics.
// 4 edges per wave-instruction: 16 lanes/edge x uint2 (8B = 4 bf16 channels).
// Dword-path loads (fast), 2 cache lines per edge, 800k gather instrs total.
__global__ __launch_bounds__(256) void k_agg2(const int* __restrict__ csr,
                                              const int* __restrict__ offs,
                                              const int* __restrict__ cnt,
                                              const float* __restrict__ dinv,
                                              const float* __restrict__ b2,
                                              const unsigned short* __restrict__ g2b,
                                              const int* __restrict__ batch,
                                              float* __restrict__ pooled,
                                              int* __restrict__ cntg) {
    int lane = threadIdx.x & 63;
    int v = (blockIdx.x * 256 + threadIdx.x) >> 6;
    if (v >= N) return;
    int g = lane >> 4;   // edge slot 0..3
    int q = lane & 15;   // row quarter: channels 4q..4q+3
    int start = offs[v], dg = cnt[v];
    const uint2* g2v = (const uint2*)g2b;   // 16 uint2 per row

    float a0 = 0.f, a1 = 0.f, a2 = 0.f, a3 = 0.f;

    int base = 0;
    while (base < dg) {
        int chunk = dg - base; if (chunk > 64) chunk = 64;
        int idx = csr[start + base + lane];   // coalesced; csr padded
        int nit = (chunk + 3) >> 2;           // 4-edge iterations
        for (int it0 = 0; it0 < nit; it0 += 8) {
            uint2 u[8];
            int okm[8];
            #pragma unroll
            for (int k = 0; k < 8; ++k) {
                int it = it0 + k;
                int e = (it << 2) | g;
                bool ok = (it < nit) && (e < chunk);
                okm[k] = ok ? -1 : 0;
                int ec = ok ? e : 0;
                int row = __shfl(idx, ec);    // per-16-lane-group broadcast
                u[k] = g2v[((size_t)row << 4) + q];
            }
            #pragma unroll
            for (int k = 0; k < 8; ++k) {
                unsigned int ux = u[k].x & (unsigned int)okm[k];
                unsigned int uy = u[k].y & (unsigned int)okm[k];
                a0 += bflo(ux); a1 += bfhi(ux);
                a2 += bflo(uy); a3 += bfhi(uy);
            }
        }
        base += chunk;
    }

    // reduce across the 4 edge slots (butterfly over lane bits 4,5)
    a0 += __shfl_xor(a0, 16); a0 += __shfl_xor(a0, 32);
    a1 += __shfl_xor(a1, 16); a1 += __shfl_xor(a1, 32);
    a2 += __shfl_xor(a2, 16); a2 += __shfl_xor(a2, 32);
    a3 += __shfl_xor(a3, 16); a3 += __shfl_xor(a3, 32);

    if (g == 0) {  // lanes 0..15 finalize 4 channels each
        uint2 s = g2v[((size_t)v << 4) + q];   // self-loop term
        a0 += bflo(s.x); a1 += bfhi(s.x);
        a2 += bflo(s.y); a3 += bfhi(s.y);
        float d = dinv[v];
        int c0 = q << 2;
        float o0 = fmaxf(fmaf(d, a0, b2[c0 + 0]), 0.f);
        float o1 = fmaxf(fmaf(d, a1, b2[c0 + 1]), 0.f);
        float o2 = fmaxf(fmaf(d, a2, b2[c0 + 2]), 0.f);
        float o3 = fmaxf(fmaf(d, a3, b2[c0 + 3]), 0.f);
        int b = batch[v];
        atomicAdd(&pooled[b * 64 + c0 + 0], o0);
        atomicAdd(&pooled[b * 64 + c0 + 1], o1);
        atomicAdd(&pooled[b * 64 + c0 + 2], o2);
        atomicAdd(&pooled[b * 64 + c0 + 3], o3);
        if (lane == 0) atomicAdd(&cntg[b], 1);
    }
}

// K8: final: out[g] = (pooled[g]/max(cnt,1)) . Wfc + bfc
__global__ __launch_bounds__(64) void k_final(const float* __restrict__ pooled,
                                              const int* __restrict__ cntg,
                                              const float* __restrict__ Wfc,
                                              const float* __restrict__ bfc,
                                              float* __restrict__ out) {
    int g = blockIdx.x;
    int j = threadIdx.x;  // 64
    float c = fmaxf((float)cntg[g], 1.f);
    float p = (pooled[g * 64 + j] / c) * Wfc[j];
    #pragma unroll
    for (int off = 32; off >= 1; off >>= 1) p += __shfl_down(p, off);
    if (j == 0) out[g] = p + bfc[0];
}

// ---------------------------------------------------------------------------
extern "C" void kernel_launch(void* const* d_in, const int* in_sizes, int n_in,
                              void* d_out, int out_size, void* d_ws, size_t ws_size,
                              hipStream_t stream) {
    const float* x     = (const float*)d_in[0];
    const int*   edge  = (const int*)d_in[1];
    const int*   batch = (const int*)d_in[2];
    const float* W1    = (const float*)d_in[3];
    const float* b1    = (const float*)d_in[4];
    const float* W2    = (const float*)d_in[5];
    const float* b2    = (const float*)d_in[6];
    const float* Wfc   = (const float*)d_in[7];
    const float* bfc   = (const float*)d_in[8];
    float* out = (float*)d_out;

    const int* src = edge;       // edge_index[0]
    const int* dst = edge + E;   // edge_index[1]

    // workspace layout (1 KiB aligned regions)
    char* base = (char*)d_ws;
    size_t o = 0;
    auto alloc = [&](size_t bytes) -> void* {
        void* p = base + o;
        o += (bytes + 1023) & ~size_t(1023);
        return p;
    };
    int*    cnt    = (int*)alloc((size_t)N * 4);
    float*  dinv   = (float*)alloc((size_t)N * 4);
    float2* gx     = (float2*)alloc((size_t)N * 8);
    float2* aggx   = (float2*)alloc((size_t)N * 8);
    int*    offs   = (int*)alloc((size_t)N * 4);
    int*    cursor = (int*)alloc((size_t)N * 4);
    int*    csr    = (int*)alloc((size_t)E * 4 + 1024);   // +pad for 64-lane over-read
    unsigned short* g2b = (unsigned short*)alloc((size_t)N * H * 2);  // bf16 rows
    float*  pooled = (float*)alloc((size_t)G * H * 4);
    int*    cntg   = (int*)alloc((size_t)G * 4);

    hipMemsetAsync(cnt, 0, (size_t)N * 4, stream);
    hipMemsetAsync(pooled, 0, (size_t)G * H * 4, stream);
    hipMemsetAsync(cntg, 0, (size_t)G * 4, stream);

    k_count<<<(E + 255) / 256, 256, 0, stream>>>(dst, cnt);
    k_dinv<<<(N + 255) / 256, 256, 0, stream>>>(x, cnt, dinv, gx);
    k_scan<<<1, 1024, 0, stream>>>(cnt, offs, cursor);
    k_fill<<<(E + 255) / 256, 256, 0, stream>>>(src, dst, cursor, csr);
    k_agg1<<<(N + 3) / 4, 256, 0, stream>>>(csr, offs, cnt, dinv, gx, aggx);
    k_mlp<<<1024, 256, 0, stream>>>(aggx, W1, b1, W2, dinv, g2b);
    k_agg2<<<(N + 3) / 4, 256, 0, stream>>>(csr, offs, cnt, dinv, b2, g2b, batch, pooled, cntg);
    k_final<<<G, 64, 0, stream>>>(pooled, cntg, Wfc, bfc, out);
}

// Round 15
// 1342.290 us; speedup vs baseline: 1.4134x; 1.0710x over previous
//
#include <hip/hip_runtime.h>

// Problem constants (match reference)
constexpr int N  = 100000;   // nodes
constexpr int E  = 3200000;  // edges
constexpr int G  = 128;      // graphs
constexpr int H  = 64;       // hidden

__device__ __forceinline__ unsigned short f32_to_bf16_rne(float x) {
    unsigned int u = __float_as_uint(x);
    unsigned int r = (u + 0x7FFFu + ((u >> 16) & 1u)) >> 16;
    return (unsigned short)r;
}
__device__ __forceinline__ float bflo(unsigned int u) { return __uint_as_float(u << 16); }
__device__ __forceinline__ float bfhi(unsigned int u) { return __uint_as_float(u & 0xFFFF0000u); }

// ---------------------------------------------------------------------------
// K1: in-degree counts (dst occurrences); self-loop added later as +1
__global__ __launch_bounds__(256) void k_count(const int* __restrict__ dst,
                                               int* __restrict__ cnt) {
    int e = blockIdx.x * 256 + threadIdx.x;
    if (e < E) atomicAdd(&cnt[dst[e]], 1);
}

// K2: dinv = rsqrt(deg), gx = x * dinv (pre-scaled 2-channel features)
__global__ __launch_bounds__(256) void k_dinv(const float* __restrict__ x,
                                              const int* __restrict__ cnt,
                                              float* __restrict__ dinv,
                                              float2* __restrict__ gx) {
    int v = blockIdx.x * 256 + threadIdx.x;
    if (v < N) {
        float d = rsqrtf((float)(cnt[v] + 1));
        dinv[v] = d;
        float2 xv = ((const float2*)x)[v];
        gx[v] = make_float2(xv.x * d, xv.y * d);
    }
}

// K3: single-block exclusive scan of cnt -> offs (and cursor copy).
__global__ __launch_bounds__(1024) void k_scan(const int* __restrict__ cnt,
                                               int* __restrict__ offs,
                                               int* __restrict__ cursor) {
    constexpr int T = 1024;
    constexpr int PER = (N + T - 1) / T;  // 98
    int tid = threadIdx.x;
    int begin = tid * PER;
    int end = begin + PER; if (end > N) end = N;

    int total = 0;
    for (int i = begin; i < end; ++i) total += cnt[i];

    __shared__ int wsum[16];
    int lane = tid & 63, wid = tid >> 6;
    int incl = total;
    #pragma unroll
    for (int off = 1; off < 64; off <<= 1) {
        int t = __shfl_up(incl, off);
        if (lane >= off) incl += t;
    }
    if (lane == 63) wsum[wid] = incl;
    __syncthreads();
    if (wid == 0 && lane < 16) {
        int w = wsum[lane];
        #pragma unroll
        for (int off = 1; off < 16; off <<= 1) {
            int t = __shfl_up(w, off);
            if (lane >= off) w += t;
        }
        wsum[lane] = w;  // inclusive over waves
    }
    __syncthreads();
    int waveBase = (wid == 0) ? 0 : wsum[wid - 1];
    int run = waveBase + (incl - total);  // exclusive prefix of this thread
    for (int i = begin; i < end; ++i) {
        offs[i] = run;
        cursor[i] = run;
        run += cnt[i];
    }
}

// K4: fill CSR (src indices grouped by dst)
__global__ __launch_bounds__(256) void k_fill(const int* __restrict__ src,
                                              const int* __restrict__ dst,
                                              int* __restrict__ cursor,
                                              int* __restrict__ csr) {
    int e = blockIdx.x * 256 + threadIdx.x;
    if (e < E) {
        int d = dst[e];
        int pos = atomicAdd(&cursor[d], 1);
        csr[pos] = src[e];
    }
}

// K5: layer-1 aggregation in 2-channel input space. One wave per node,
// lane-per-edge: coalesced index load + 64 independent 8B gathers in flight.
__global__ __launch_bounds__(256) void k_agg1(const int* __restrict__ csr,
                                              const int* __restrict__ offs,
                                              const int* __restrict__ cnt,
                                              const float* __restrict__ dinv,
                                              const float2* __restrict__ gx,
                                              float2* __restrict__ aggx) {
    int lane = threadIdx.x & 63;
    int v = (blockIdx.x * 256 + threadIdx.x) >> 6;
    if (v >= N) return;
    int start = offs[v], dg = cnt[v];
    float ax = 0.f, ay = 0.f;
    for (int i = lane; i < dg; i += 64) {
        int s = csr[start + i];
        float2 g = gx[s];
        ax += g.x; ay += g.y;
    }
    #pragma unroll
    for (int off = 1; off < 64; off <<= 1) {
        ax += __shfl_xor(ax, off);
        ay += __shfl_xor(ay, off);
    }
    if (lane == 0) {
        float d = dinv[v];
        float2 g = gx[v];
        aggx[v] = make_float2(d * (ax + g.x), d * (ay + g.y));
    }
}

// K6: per-node MLP: t = relu(aggx @ W1 + b1); g2 = (t @ W2) * dinv[v]
// Output stored as bf16 rows [v][64] (128B rows, 2 cache lines).
__global__ __launch_bounds__(256) void k_mlp(const float2* __restrict__ aggx,
                                             const float* __restrict__ W1,
                                             const float* __restrict__ b1,
                                             const float* __restrict__ W2,
                                             const float* __restrict__ dinv,
                                             unsigned short* __restrict__ g2b) {
    int lane = threadIdx.x & 63;
    int wave = (blockIdx.x * 256 + threadIdx.x) >> 6;
    int nw = gridDim.x * 4;

    float w2col[64];
    #pragma unroll
    for (int k = 0; k < 64; ++k) w2col[k] = W2[k * 64 + lane];
    float w10 = W1[lane], w11 = W1[64 + lane], bb = b1[lane];

    for (int v = wave; v < N; v += nw) {
        float2 a = aggx[v];
        float tt = fmaxf(fmaf(a.y, w11, fmaf(a.x, w10, bb)), 0.f);
        float a0 = 0.f, a1 = 0.f, a2 = 0.f, a3 = 0.f;
        #pragma unroll
        for (int k = 0; k < 64; k += 4) {
            float t0 = __int_as_float(__builtin_amdgcn_readlane(__float_as_int(tt), k + 0));
            float t1 = __int_as_float(__builtin_amdgcn_readlane(__float_as_int(tt), k + 1));
            float t2 = __int_as_float(__builtin_amdgcn_readlane(__float_as_int(tt), k + 2));
            float t3 = __int_as_float(__builtin_amdgcn_readlane(__float_as_int(tt), k + 3));
            a0 = fmaf(t0, w2col[k + 0], a0);
            a1 = fmaf(t1, w2col[k + 1], a1);
            a2 = fmaf(t2, w2col[k + 2], a2);
            a3 = fmaf(t3, w2col[k + 3], a3);
        }
        float val = ((a0 + a1) + (a2 + a3)) * dinv[v];
        g2b[(size_t)v * 64 + lane] = f32_to_bf16_rne(val);
    }
}

// K7: layer-2 aggregation + relu + fused mean-pool atomics.
// R2-shaped coalescing on the bf16 table: 2 edges per wave-instruction,
// 32 lanes x 4B (uint = 2 bf16 channels) per edge -> contiguous 128B dword
// runs = 4 full-line requests/instr on the proven-fast path. 1.6M instrs,
// 6.4M line-events total.
__global__ __launch_bounds__(256) void k_agg2(const int* __restrict__ csr,
                                              const int* __restrict__ offs,
                                              const int* __restrict__ cnt,
                                              const float* __restrict__ dinv,
                                              const float* __restrict__ b2,
                                              const unsigned short* __restrict__ g2b,
                                              const int* __restrict__ batch,
                                              float* __restrict__ pooled,
                                              int* __restrict__ cntg) {
    int lane = threadIdx.x & 63;
    int v = (blockIdx.x * 256 + threadIdx.x) >> 6;
    if (v >= N) return;
    int half = lane >> 5;   // 0: even edge slot, 1: odd edge slot
    int c = lane & 31;      // uint index within row (channels 2c, 2c+1)
    int start = offs[v], dg = cnt[v];
    const unsigned int* g2u = (const unsigned int*)g2b;  // 32 uints per row

    float aLo = 0.f, aHi = 0.f;

    int base = 0;
    while (base < dg) {
        int chunk = dg - base; if (chunk > 64) chunk = 64;
        int idx = csr[start + base + lane];   // coalesced; csr padded
        int npair = (chunk + 1) >> 1;
        for (int p0 = 0; p0 < npair; p0 += 8) {
            unsigned int u[8];
            int okm[8];
            #pragma unroll
            for (int k = 0; k < 8; ++k) {
                int p = p0 + k;
                int e = (p << 1) | half;
                bool ok = (p < npair) && (e < chunk);
                okm[k] = ok ? -1 : 0;
                int jA = p << 1;       if (jA > chunk - 1) jA = chunk - 1;  // wave-uniform clamp
                int jB = (p << 1) | 1; if (jB > chunk - 1) jB = chunk - 1;
                int rA = __builtin_amdgcn_readlane(idx, jA);
                int rB = __builtin_amdgcn_readlane(idx, jB);
                int row = half ? rB : rA;     // one cndmask
                u[k] = g2u[((size_t)row << 5) + c];
            }
            #pragma unroll
            for (int k = 0; k < 8; ++k) {
                unsigned int uu = u[k] & (unsigned int)okm[k];
                aLo += bflo(uu);
                aHi += bfhi(uu);
            }
        }
        base += chunk;
    }

    // combine even/odd edge-slot partials (channel pair identical across halves)
    aLo += __shfl_xor(aLo, 32);
    aHi += __shfl_xor(aHi, 32);

    if (half == 0) {  // lanes 0..31 finalize channels 2c, 2c+1
        unsigned int s = g2u[((size_t)v << 5) + c];   // self-loop term
        aLo += bflo(s);
        aHi += bfhi(s);
        float d = dinv[v];
        int c0 = c << 1;
        float o0 = fmaxf(fmaf(d, aLo, b2[c0 + 0]), 0.f);
        float o1 = fmaxf(fmaf(d, aHi, b2[c0 + 1]), 0.f);
        int b = batch[v];
        atomicAdd(&pooled[b * 64 + c0 + 0], o0);
        atomicAdd(&pooled[b * 64 + c0 + 1], o1);
        if (lane == 0) atomicAdd(&cntg[b], 1);
    }
}

// K8: final: out[g] = (pooled[g]/max(cnt,1)) . Wfc + bfc
__global__ __launch_bounds__(64) void k_final(const float* __restrict__ pooled,
                                              const int* __restrict__ cntg,
                                              const float* __restrict__ Wfc,
                                              const float* __restrict__ bfc,
                                              float* __restrict__ out) {
    int g = blockIdx.x;
    int j = threadIdx.x;  // 64
    float c = fmaxf((float)cntg[g], 1.f);
    float p = (pooled[g * 64 + j] / c) * Wfc[j];
    #pragma unroll
    for (int off = 32; off >= 1; off >>= 1) p += __shfl_down(p, off);
    if (j == 0) out[g] = p + bfc[0];
}

// ---------------------------------------------------------------------------
extern "C" void kernel_launch(void* const* d_in, const int* in_sizes, int n_in,
                              void* d_out, int out_size, void* d_ws, size_t ws_size,
                              hipStream_t stream) {
    const float* x     = (const float*)d_in[0];
    const int*   edge  = (const int*)d_in[1];
    const int*   batch = (const int*)d_in[2];
    const float* W1    = (const float*)d_in[3];
    const float* b1    = (const float*)d_in[4];
    const float* W2    = (const float*)d_in[5];
    const float* b2    = (const float*)d_in[6];
    const float* Wfc   = (const float*)d_in[7];
    const float* bfc   = (const float*)d_in[8];
    float* out = (float*)d_out;

    const int* src = edge;       // edge_index[0]
    const int* dst = edge + E;   // edge_index[1]

    // workspace layout (1 KiB aligned regions)
    char* base = (char*)d_ws;
    size_t o = 0;
    auto alloc = [&](size_t bytes) -> void* {
        void* p = base + o;
        o += (bytes + 1023) & ~size_t(1023);
        return p;
    };
    int*    cnt    = (int*)alloc((size_t)N * 4);
    float*  dinv   = (float*)alloc((size_t)N * 4);
    float2* gx     = (float2*)alloc((size_t)N * 8);
    float2* aggx   = (float2*)alloc((size_t)N * 8);
    int*    offs   = (int*)alloc((size_t)N * 4);
    int*    cursor = (int*)alloc((size_t)N * 4);
    int*    csr    = (int*)alloc((size_t)E * 4 + 1024);   // +pad for 64-lane over-read
    unsigned short* g2b = (unsigned short*)alloc((size_t)N * H * 2);  // bf16 rows
    float*  pooled = (float*)alloc((size_t)G * H * 4);
    int*    cntg   = (int*)alloc((size_t)G * 4);

    hipMemsetAsync(cnt, 0, (size_t)N * 4, stream);
    hipMemsetAsync(pooled, 0, (size_t)G * H * 4, stream);
    hipMemsetAsync(cntg, 0, (size_t)G * 4, stream);

    k_count<<<(E + 255) / 256, 256, 0, stream>>>(dst, cnt);
    k_dinv<<<(N + 255) / 256, 256, 0, stream>>>(x, cnt, dinv, gx);
    k_scan<<<1, 1024, 0, stream>>>(cnt, offs, cursor);
    k_fill<<<(E + 255) / 256, 256, 0, stream>>>(src, dst, cursor, csr);
    k_agg1<<<(N + 3) / 4, 256, 0, stream>>>(csr, offs, cnt, dinv, gx, aggx);
    k_mlp<<<1024, 256, 0, stream>>>(aggx, W1, b1, W2, dinv, g2b);
    k_agg2<<<(N + 3) / 4, 256, 0, stream>>>(csr, offs, cnt, dinv, b2, g2b, batch, pooled, cntg);
    k_final<<<G, 64, 0, stream>>>(pooled, cntg, Wfc, bfc, out);
}

// Round 16
// 1083.586 us; speedup vs baseline: 1.7509x; 1.2387x over previous
//
#include <hip/hip_runtime.h>

// Problem constants (match reference)
constexpr int N  = 100000;   // nodes
constexpr int E  = 3200000;  // edges
constexpr int G  = 128;      // graphs
constexpr int H  = 64;       // hidden
constexpr int NT   = 4;      // src tiles (3.2MB bf16 rows per tile -> L2-resident)
constexpr int TILE = 25000;  // nodes per src tile
constexpr int M4   = NT * N; // 400000 (tile,dst) counters
constexpr int NB   = (M4 + 1023) / 1024;  // scan blocks (391)

__device__ __forceinline__ unsigned short f32_to_bf16_rne(float x) {
    unsigned int u = __float_as_uint(x);
    unsigned int r = (u + 0x7FFFu + ((u >> 16) & 1u)) >> 16;
    return (unsigned short)r;
}
__device__ __forceinline__ float bflo(unsigned int u) { return __uint_as_float(u << 16); }
__device__ __forceinline__ float bfhi(unsigned int u) { return __uint_as_float(u & 0xFFFF0000u); }

// ---------------------------------------------------------------------------
// K1: per-(src-tile, dst) counts. 1.6MB counter table = L2-resident atomics.
__global__ __launch_bounds__(256) void k_count4(const int* __restrict__ src,
                                                const int* __restrict__ dst,
                                                int* __restrict__ cnt4) {
    int e = blockIdx.x * 256 + threadIdx.x;
    if (e < E) {
        int t = src[e] / TILE;
        atomicAdd(&cnt4[t * N + dst[e]], 1);
    }
}

// K2: dinv = rsqrt(deg) (deg = total in-degree + self), gx = x * dinv
__global__ __launch_bounds__(256) void k_dinv(const float* __restrict__ x,
                                              const int* __restrict__ cnt4,
                                              float* __restrict__ dinv,
                                              float2* __restrict__ gx) {
    int v = blockIdx.x * 256 + threadIdx.x;
    if (v < N) {
        int deg = cnt4[v] + cnt4[N + v] + cnt4[2 * N + v] + cnt4[3 * N + v] + 1;
        float d = rsqrtf((float)deg);
        dinv[v] = d;
        float2 xv = ((const float2*)x)[v];
        gx[v] = make_float2(xv.x * d, xv.y * d);
    }
}

// ---- hierarchical exclusive scan of cnt4[M4] -> offs4 (3 kernels) ----------
__global__ __launch_bounds__(1024) void k_scan1(const int* __restrict__ cnt4,
                                                int* __restrict__ offs4,
                                                int* __restrict__ blksum) {
    int i = blockIdx.x * 1024 + threadIdx.x;
    int v = (i < M4) ? cnt4[i] : 0;
    int lane = threadIdx.x & 63, wid = threadIdx.x >> 6;  // 16 waves
    int incl = v;
    #pragma unroll
    for (int off = 1; off < 64; off <<= 1) {
        int t = __shfl_up(incl, off);
        if (lane >= off) incl += t;
    }
    __shared__ int ws[16];
    if (lane == 63) ws[wid] = incl;
    __syncthreads();
    if (wid == 0 && lane < 16) {
        int w = ws[lane];
        #pragma unroll
        for (int off = 1; off < 16; off <<= 1) {
            int t = __shfl_up(w, off);
            if (lane >= off) w += t;
        }
        ws[lane] = w;  // inclusive over waves
    }
    __syncthreads();
    int base = (wid == 0) ? 0 : ws[wid - 1];
    if (i < M4) offs4[i] = base + incl - v;  // block-local exclusive
    if (threadIdx.x == 0) blksum[blockIdx.x] = ws[15];
}

__global__ __launch_bounds__(512) void k_scan2(int* __restrict__ blksum) {
    int i = threadIdx.x;  // 512 >= NB
    int v = (i < NB) ? blksum[i] : 0;
    int lane = i & 63, wid = i >> 6;  // 8 waves
    int incl = v;
    #pragma unroll
    for (int off = 1; off < 64; off <<= 1) {
        int t = __shfl_up(incl, off);
        if (lane >= off) incl += t;
    }
    __shared__ int ws[8];
    if (lane == 63) ws[wid] = incl;
    __syncthreads();
    if (wid == 0 && lane < 8) {
        int w = ws[lane];
        #pragma unroll
        for (int off = 1; off < 8; off <<= 1) {
            int t = __shfl_up(w, off);
            if (lane >= off) w += t;
        }
        ws[lane] = w;
    }
    __syncthreads();
    int base = (wid == 0) ? 0 : ws[wid - 1];
    if (i < NB) blksum[i] = base + incl - v;  // exclusive block bases
}

__global__ __launch_bounds__(1024) void k_scan3(int* __restrict__ offs4,
                                                int* __restrict__ cursor4,
                                                const int* __restrict__ blksum) {
    int i = blockIdx.x * 1024 + threadIdx.x;
    if (i < M4) {
        int o = offs4[i] + blksum[blockIdx.x];
        offs4[i] = o;
        cursor4[i] = o;
    }
}

// K4 (x NT passes): fill CSR for tile t. Scatter lands in a ~3.2MB region
// (L2-resident) + cursor slice (400KB, L2-resident atomics).
__global__ __launch_bounds__(256) void k_fill4(const int* __restrict__ src,
                                               const int* __restrict__ dst,
                                               int* __restrict__ cursor4,
                                               int* __restrict__ csr,
                                               int t) {
    int e = blockIdx.x * 256 + threadIdx.x;
    if (e < E) {
        int s = src[e];
        if (s / TILE == t) {
            int pos = atomicAdd(&cursor4[t * N + dst[e]], 1);
            csr[pos] = s;
        }
    }
}

// K5: layer-1 aggregation over 4 segments; gx (800KB) is L2-resident.
__global__ __launch_bounds__(256) void k_agg1(const int* __restrict__ csr,
                                              const int* __restrict__ offs4,
                                              const int* __restrict__ cnt4,
                                              const float* __restrict__ dinv,
                                              const float2* __restrict__ gx,
                                              float2* __restrict__ aggx) {
    int lane = threadIdx.x & 63;
    int v = (blockIdx.x * 256 + threadIdx.x) >> 6;
    if (v >= N) return;
    float ax = 0.f, ay = 0.f;
    #pragma unroll
    for (int t = 0; t < NT; ++t) {
        int st = offs4[t * N + v], len = cnt4[t * N + v];
        for (int i = lane; i < len; i += 64) {
            int s = csr[st + i];
            float2 g = gx[s];
            ax += g.x; ay += g.y;
        }
    }
    #pragma unroll
    for (int off = 1; off < 64; off <<= 1) {
        ax += __shfl_xor(ax, off);
        ay += __shfl_xor(ay, off);
    }
    if (lane == 0) {
        float d = dinv[v];
        float2 g = gx[v];
        aggx[v] = make_float2(d * (ax + g.x), d * (ay + g.y));
    }
}

// K6: per-node MLP: t = relu(aggx @ W1 + b1); g2 = (t @ W2) * dinv[v]
// Output bf16 rows [v][64] (128B).
__global__ __launch_bounds__(256) void k_mlp(const float2* __restrict__ aggx,
                                             const float* __restrict__ W1,
                                             const float* __restrict__ b1,
                                             const float* __restrict__ W2,
                                             const float* __restrict__ dinv,
                                             unsigned short* __restrict__ g2b) {
    int lane = threadIdx.x & 63;
    int wave = (blockIdx.x * 256 + threadIdx.x) >> 6;
    int nw = gridDim.x * 4;

    float w2col[64];
    #pragma unroll
    for (int k = 0; k < 64; ++k) w2col[k] = W2[k * 64 + lane];
    float w10 = W1[lane], w11 = W1[64 + lane], bb = b1[lane];

    for (int v = wave; v < N; v += nw) {
        float2 a = aggx[v];
        float tt = fmaxf(fmaf(a.y, w11, fmaf(a.x, w10, bb)), 0.f);
        float a0 = 0.f, a1 = 0.f, a2 = 0.f, a3 = 0.f;
        #pragma unroll
        for (int k = 0; k < 64; k += 4) {
            float t0 = __int_as_float(__builtin_amdgcn_readlane(__float_as_int(tt), k + 0));
            float t1 = __int_as_float(__builtin_amdgcn_readlane(__float_as_int(tt), k + 1));
            float t2 = __int_as_float(__builtin_amdgcn_readlane(__float_as_int(tt), k + 2));
            float t3 = __int_as_float(__builtin_amdgcn_readlane(__float_as_int(tt), k + 3));
            a0 = fmaf(t0, w2col[k + 0], a0);
            a1 = fmaf(t1, w2col[k + 1], a1);
            a2 = fmaf(t2, w2col[k + 2], a2);
            a3 = fmaf(t3, w2col[k + 3], a3);
        }
        float val = ((a0 + a1) + (a2 + a3)) * dinv[v];
        g2b[(size_t)v * 64 + lane] = f32_to_bf16_rne(val);
    }
}

// K7 (x NT passes): layer-2 aggregation over tile t's L2-resident 3.2MB rows.
// MODE 0: first pass (store acc); 1: middle (acc += ); 2: last (finalize).
// Gather shape: 2 edges/instr, 32 lanes x 4B (uint = 2 bf16 ch) per edge.
template<int MODE>
__global__ __launch_bounds__(256) void k_agg2t(const int* __restrict__ csr,
                                               const int* __restrict__ offs4,
                                               const int* __restrict__ cnt4,
                                               const float* __restrict__ dinv,
                                               const float* __restrict__ b2,
                                               const unsigned short* __restrict__ g2b,
                                               const int* __restrict__ batch,
                                               float2* __restrict__ acc2,   // [N][32]
                                               float* __restrict__ pooled,
                                               int* __restrict__ cntg,
                                               int t) {
    int lane = threadIdx.x & 63;
    int v = (blockIdx.x * 256 + threadIdx.x) >> 6;
    if (v >= N) return;
    int half = lane >> 5;   // 0: even edge slot, 1: odd edge slot
    int c = lane & 31;      // uint index within row (channels 2c, 2c+1)
    int st = offs4[t * N + v], dg = cnt4[t * N + v];
    const unsigned int* g2u = (const unsigned int*)g2b;  // 32 uints per row

    float aLo = 0.f, aHi = 0.f;

    int base = 0;
    while (base < dg) {
        int chunk = dg - base; if (chunk > 64) chunk = 64;
        int idx = csr[st + base + lane];   // over-read masked; csr padded
        int npair = (chunk + 1) >> 1;
        for (int p0 = 0; p0 < npair; p0 += 8) {
            unsigned int u[8];
            int okm[8];
            #pragma unroll
            for (int k = 0; k < 8; ++k) {
                int p = p0 + k;
                int e = (p << 1) | half;
                bool ok = (p < npair) && (e < chunk);
                okm[k] = ok ? -1 : 0;
                int jA = p << 1;       if (jA > chunk - 1) jA = chunk - 1;
                int jB = (p << 1) | 1; if (jB > chunk - 1) jB = chunk - 1;
                int rA = __builtin_amdgcn_readlane(idx, jA);
                int rB = __builtin_amdgcn_readlane(idx, jB);
                int row = half ? rB : rA;
                u[k] = g2u[((size_t)row << 5) + c];
            }
            #pragma unroll
            for (int k = 0; k < 8; ++k) {
                unsigned int uu = u[k] & (unsigned int)okm[k];
                aLo += bflo(uu);
                aHi += bfhi(uu);
            }
        }
        base += chunk;
    }

    aLo += __shfl_xor(aLo, 32);
    aHi += __shfl_xor(aHi, 32);

    if (half == 0) {  // lanes 0..31: channels 2c, 2c+1
        size_t ai = (size_t)v * 32 + c;
        if (MODE == 0) {
            acc2[ai] = make_float2(aLo, aHi);
        } else if (MODE == 1) {
            float2 p = acc2[ai];
            acc2[ai] = make_float2(p.x + aLo, p.y + aHi);
        } else {
            float2 p = acc2[ai];
            unsigned int s = g2u[((size_t)v << 5) + c];   // self-loop (coalesced)
            float sLo = p.x + aLo + bflo(s);
            float sHi = p.y + aHi + bfhi(s);
            float d = dinv[v];
            int c0 = c << 1;
            float o0 = fmaxf(fmaf(d, sLo, b2[c0 + 0]), 0.f);
            float o1 = fmaxf(fmaf(d, sHi, b2[c0 + 1]), 0.f);
            int b = batch[v];
            atomicAdd(&pooled[b * 64 + c0 + 0], o0);
            atomicAdd(&pooled[b * 64 + c0 + 1], o1);
            if (lane == 0) atomicAdd(&cntg[b], 1);
        }
    }
}

// K8: final: out[g] = (pooled[g]/max(cnt,1)) . Wfc + bfc
__global__ __launch_bounds__(64) void k_final(const float* __restrict__ pooled,
                                              const int* __restrict__ cntg,
                                              const float* __restrict__ Wfc,
                                              const float* __restrict__ bfc,
                                              float* __restrict__ out) {
    int g = blockIdx.x;
    int j = threadIdx.x;  // 64
    float c = fmaxf((float)cntg[g], 1.f);
    float p = (pooled[g * 64 + j] / c) * Wfc[j];
    #pragma unroll
    for (int off = 32; off >= 1; off >>= 1) p += __shfl_down(p, off);
    if (j == 0) out[g] = p + bfc[0];
}

// ---------------------------------------------------------------------------
extern "C" void kernel_launch(void* const* d_in, const int* in_sizes, int n_in,
                              void* d_out, int out_size, void* d_ws, size_t ws_size,
                              hipStream_t stream) {
    const float* x     = (const float*)d_in[0];
    const int*   edge  = (const int*)d_in[1];
    const int*   batch = (const int*)d_in[2];
    const float* W1    = (const float*)d_in[3];
    const float* b1    = (const float*)d_in[4];
    const float* W2    = (const float*)d_in[5];
    const float* b2    = (const float*)d_in[6];
    const float* Wfc   = (const float*)d_in[7];
    const float* bfc   = (const float*)d_in[8];
    float* out = (float*)d_out;

    const int* src = edge;       // edge_index[0]
    const int* dst = edge + E;   // edge_index[1]

    // workspace layout (1 KiB aligned regions), ~58 MB total
    char* base = (char*)d_ws;
    size_t o = 0;
    auto alloc = [&](size_t bytes) -> void* {
        void* p = base + o;
        o += (bytes + 1023) & ~size_t(1023);
        return p;
    };
    int*    cnt4    = (int*)alloc((size_t)M4 * 4);        // 1.6MB
    int*    offs4   = (int*)alloc((size_t)M4 * 4);
    int*    cursor4 = (int*)alloc((size_t)M4 * 4);
    int*    blksum  = (int*)alloc((size_t)NB * 4);
    float*  dinv    = (float*)alloc((size_t)N * 4);
    float2* gx      = (float2*)alloc((size_t)N * 8);
    float2* aggx    = (float2*)alloc((size_t)N * 8);
    int*    csr     = (int*)alloc((size_t)E * 4 + 1024);  // +pad for over-read
    unsigned short* g2b = (unsigned short*)alloc((size_t)N * H * 2);  // 12.8MB
    float2* acc2    = (float2*)alloc((size_t)N * 32 * 8); // 25.6MB fp32 acc
    float*  pooled  = (float*)alloc((size_t)G * H * 4);
    int*    cntg    = (int*)alloc((size_t)G * 4);

    hipMemsetAsync(cnt4, 0, (size_t)M4 * 4, stream);
    hipMemsetAsync(pooled, 0, (size_t)G * H * 4, stream);
    hipMemsetAsync(cntg, 0, (size_t)G * 4, stream);

    k_count4<<<(E + 255) / 256, 256, 0, stream>>>(src, dst, cnt4);
    k_dinv<<<(N + 255) / 256, 256, 0, stream>>>(x, cnt4, dinv, gx);
    k_scan1<<<NB, 1024, 0, stream>>>(cnt4, offs4, blksum);
    k_scan2<<<1, 512, 0, stream>>>(blksum);
    k_scan3<<<NB, 1024, 0, stream>>>(offs4, cursor4, blksum);
    for (int t = 0; t < NT; ++t)
        k_fill4<<<(E + 255) / 256, 256, 0, stream>>>(src, dst, cursor4, csr, t);
    k_agg1<<<(N + 3) / 4, 256, 0, stream>>>(csr, offs4, cnt4, dinv, gx, aggx);
    k_mlp<<<1024, 256, 0, stream>>>(aggx, W1, b1, W2, dinv, g2b);
    // layer-2: 4 sequential src-tile passes, each tile's rows L2-resident
    k_agg2t<0><<<(N + 3) / 4, 256, 0, stream>>>(csr, offs4, cnt4, dinv, b2, g2b,
                                                batch, acc2, pooled, cntg, 0);
    k_agg2t<1><<<(N + 3) / 4, 256, 0, stream>>>(csr, offs4, cnt4, dinv, b2, g2b,
                                                batch, acc2, pooled, cntg, 1);
    k_agg2t<1><<<(N + 3) / 4, 256, 0, stream>>>(csr, offs4, cnt4, dinv, b2, g2b,
                                                batch, acc2, pooled, cntg, 2);
    k_agg2t<2><<<(N + 3) / 4, 256, 0, stream>>>(csr, offs4, cnt4, dinv, b2, g2b,
                                                batch, acc2, pooled, cntg, 3);
    k_final<<<G, 64, 0, stream>>>(pooled, cntg, Wfc, bfc, out);
}